// Round 1
// baseline (1247.636 us; speedup 1.0000x reference)
//
#include <hip/hip_runtime.h>
#include <hip/hip_bf16.h>

// GPT2 attention: hidden[2,2048,1024] -> qkv gemm -> causal flash attn -> proj
// ws layout (needs 48 MB):
//   hA     bf16 [4096,1024]  @ 0      (8 MB)
//   wqkvT  bf16 [3072,1024]  @ 8 MB   (6 MB)   (w_attn transposed)
//   wprojT bf16 [1024,1024]  @ 14 MB  (2 MB)
//   qkv    bf16 [4096,3072]  @ 16 MB  (24 MB)
//   aout   bf16 [4096,1024]  @ 40 MB  (8 MB)

typedef __attribute__((ext_vector_type(4))) float  float4v;
typedef __attribute__((ext_vector_type(8))) short  short8v;
typedef __attribute__((ext_vector_type(4))) short  short4v;

__device__ __forceinline__ short f2bf(float f) {
  union { float f; unsigned u; } v; v.f = f;
  unsigned r = v.u + 0x7fffu + ((v.u >> 16) & 1u);   // RNE
  return (short)(r >> 16);
}
__device__ __forceinline__ float bf2f(short s) {
  union { unsigned u; float f; } v; v.u = ((unsigned)(unsigned short)s) << 16;
  return v.f;
}

// ---------------- fp32 -> bf16 convert (vectorized) ----------------
__global__ __launch_bounds__(256) void to_bf16_kernel(
    const float* __restrict__ in, short* __restrict__ out) {
  const size_t i = ((size_t)blockIdx.x * 256 + threadIdx.x) * 4;
  float4v v = *(const float4v*)(in + i);
  short4v o;
  #pragma unroll
  for (int k = 0; k < 4; k++) o[k] = f2bf(v[k]);
  *(short4v*)(out + i) = o;
}

// ---------------- fp32 [R,C] -> bf16 transposed [C,R] ----------------
__global__ __launch_bounds__(256) void transpose_to_bf16(
    const float* __restrict__ in, short* __restrict__ out, int R, int C) {
  __shared__ float tile[32][33];
  const int c0 = blockIdx.x * 32, r0 = blockIdx.y * 32;
  const int tx = threadIdx.x, ty = threadIdx.y;   // 32 x 8
  #pragma unroll
  for (int i = 0; i < 4; i++)
    tile[ty + i * 8][tx] = in[(size_t)(r0 + ty + i * 8) * C + c0 + tx];
  __syncthreads();
  #pragma unroll
  for (int i = 0; i < 4; i++) {
    const int cc = ty + i * 8;
    out[(size_t)(c0 + cc) * R + r0 + tx] = f2bf(tile[tx][cc]);
  }
}

// ---------------- bf16 MFMA GEMM-BT: C[M,N] = A[M,K] * Bt[N,K]^T + bias ----
// 128x128 tile, BK=32, 256 threads (4 waves in 2x2, each wave 64x64 = 4x4 MFMA)
#define BM 128
#define BN 128
#define BK 32
#define KPAD 8   // +16B per row: keeps 16B alignment, breaks bank aliasing

template<int OUT_BF16>
__global__ __launch_bounds__(256) void gemm_bt(
    const short* __restrict__ A, const short* __restrict__ Bt,
    const float* __restrict__ bias, void* __restrict__ Cout,
    int M, int N, int K)
{
  __shared__ short As[BM][BK + KPAD];
  __shared__ short Bs[BN][BK + KPAD];
  const int t    = threadIdx.x;
  const int lane = t & 63;
  const int wave = t >> 6;
  const int wm   = (wave >> 1) * 64;
  const int wn   = (wave & 1) * 64;
  const int l16  = lane & 15;
  const int quad = lane >> 4;
  const int row0 = blockIdx.y * BM;
  const int col0 = blockIdx.x * BN;

  float4v acc[4][4] = {};

  const int r_ld = t >> 2;          // 0..63
  const int c_ld = (t & 3) * 8;     // 0,8,16,24

  for (int k0 = 0; k0 < K; k0 += BK) {
    #pragma unroll
    for (int half = 0; half < 2; half++) {
      const int r = r_ld + half * 64;
      *(short8v*)&As[r][c_ld] =
          *(const short8v*)(A  + (size_t)(row0 + r) * K + k0 + c_ld);
      *(short8v*)&Bs[r][c_ld] =
          *(const short8v*)(Bt + (size_t)(col0 + r) * K + k0 + c_ld);
    }
    __syncthreads();
    short8v af[4], bf[4];
    #pragma unroll
    for (int i = 0; i < 4; i++)
      af[i] = *(const short8v*)&As[wm + i * 16 + l16][quad * 8];
    #pragma unroll
    for (int j = 0; j < 4; j++)
      bf[j] = *(const short8v*)&Bs[wn + j * 16 + l16][quad * 8];
    #pragma unroll
    for (int i = 0; i < 4; i++)
      #pragma unroll
      for (int j = 0; j < 4; j++)
        acc[i][j] = __builtin_amdgcn_mfma_f32_16x16x32_bf16(af[i], bf[j], acc[i][j], 0, 0, 0);
    __syncthreads();
  }

  // epilogue: C/D layout col=lane&15, row=quad*4+r  (m89/m91-verified)
  #pragma unroll
  for (int j = 0; j < 4; j++) {
    const int col = col0 + wn + j * 16 + l16;
    const float bv = bias[col];
    #pragma unroll
    for (int i = 0; i < 4; i++) {
      #pragma unroll
      for (int r = 0; r < 4; r++) {
        const int row = row0 + wm + i * 16 + quad * 4 + r;
        const float v = acc[i][j][r] + bv;
        if (OUT_BF16) ((short*)Cout)[(size_t)row * N + col] = f2bf(v);
        else          ((float*)Cout)[(size_t)row * N + col] = v;
      }
    }
  }
}

// ---------------- fp32 SIMT causal flash attention ----------------
// One block = one (b,h,q-tile of 64). 256 threads as (ty 0..15, tx 0..15);
// thread owns q rows {ty+16i}, k/d cols {tx+16j}  (stride-16 -> bank-friendly).
// KPs doubles as K-tile (scores phase) and P-tile (PV phase) to fit 64KB LDS.
__global__ __launch_bounds__(256) void attn_kernel(
    const short* __restrict__ qkv, short* __restrict__ out)
{
  __shared__ float Qs [64][68];
  __shared__ float KPs[64][68];
  __shared__ float Vs [64][68];

  const int qt = blockIdx.x;        // 0..31 q tiles
  const int bh = blockIdx.y;        // 0..31
  const int b  = bh >> 4;
  const int h  = bh & 15;
  const int t  = threadIdx.x;
  const int tx = t & 15;
  const int ty = t >> 4;

  const size_t base = (size_t)b * 2048 * 3072;
  const int qoff = h * 64;
  const int koff = 1024 + h * 64;
  const int voff = 2048 + h * 64;

  // stage Q tile, pre-scaled by 1/sqrt(64)
  #pragma unroll
  for (int p = 0; p < 4; p++) {
    const int r = p * 16 + ty;
    const int c = tx * 4;
    short4v v = *(const short4v*)(qkv + base + (size_t)(qt * 64 + r) * 3072 + qoff + c);
    #pragma unroll
    for (int k = 0; k < 4; k++) Qs[r][c + k] = bf2f(v[k]) * 0.125f;
  }

  float m_i[4], l_i[4], Oacc[4][4];
  #pragma unroll
  for (int i = 0; i < 4; i++) {
    m_i[i] = -INFINITY; l_i[i] = 0.0f;
    #pragma unroll
    for (int j = 0; j < 4; j++) Oacc[i][j] = 0.0f;
  }

  for (int kt = 0; kt <= qt; kt++) {
    const size_t krow = base + (size_t)(kt * 64) * 3072;
    #pragma unroll
    for (int p = 0; p < 4; p++) {
      const int r = p * 16 + ty;
      const int c = tx * 4;
      short4v kv = *(const short4v*)(qkv + krow + (size_t)r * 3072 + koff + c);
      short4v vv = *(const short4v*)(qkv + krow + (size_t)r * 3072 + voff + c);
      #pragma unroll
      for (int k = 0; k < 4; k++) { KPs[r][c + k] = bf2f(kv[k]); Vs[r][c + k] = bf2f(vv[k]); }
    }
    __syncthreads();

    // scores: S = Q K^T (4x4 micro-tile per thread)
    float s[4][4] = {};
    #pragma unroll
    for (int d = 0; d < 64; d += 4) {
      float4v qv[4], kv2[4];
      #pragma unroll
      for (int i = 0; i < 4; i++) qv[i]  = *(const float4v*)&Qs [ty + i * 16][d];
      #pragma unroll
      for (int j = 0; j < 4; j++) kv2[j] = *(const float4v*)&KPs[tx + j * 16][d];
      #pragma unroll
      for (int i = 0; i < 4; i++)
        #pragma unroll
        for (int j = 0; j < 4; j++)
          #pragma unroll
          for (int cc = 0; cc < 4; cc++)
            s[i][j] += qv[i][cc] * kv2[j][cc];
    }
    if (kt == qt) {   // diagonal tile: causal mask
      #pragma unroll
      for (int i = 0; i < 4; i++)
        #pragma unroll
        for (int j = 0; j < 4; j++)
          if (tx + j * 16 > ty + i * 16) s[i][j] = -INFINITY;
    }
    __syncthreads();   // all K reads done; KPs becomes P

    #pragma unroll
    for (int i = 0; i < 4; i++) {
      float mx = s[i][0];
      #pragma unroll
      for (int j = 1; j < 4; j++) mx = fmaxf(mx, s[i][j]);
      #pragma unroll
      for (int off = 1; off < 16; off <<= 1) mx = fmaxf(mx, __shfl_xor(mx, off));
      const float mnew  = fmaxf(m_i[i], mx);
      const float alpha = __expf(m_i[i] - mnew);
      float rs = 0.0f;
      #pragma unroll
      for (int j = 0; j < 4; j++) { const float p = __expf(s[i][j] - mnew); s[i][j] = p; rs += p; }
      #pragma unroll
      for (int off = 1; off < 16; off <<= 1) rs += __shfl_xor(rs, off);
      l_i[i] = l_i[i] * alpha + rs;
      m_i[i] = mnew;
      #pragma unroll
      for (int j = 0; j < 4; j++) {
        Oacc[i][j] *= alpha;
        KPs[ty + i * 16][tx + j * 16] = s[i][j];
      }
    }
    __syncthreads();   // P visible

    // O += P * V
    #pragma unroll
    for (int k = 0; k < 64; k += 4) {
      float4v pv[4];
      #pragma unroll
      for (int i = 0; i < 4; i++) pv[i] = *(const float4v*)&KPs[ty + i * 16][k];
      #pragma unroll
      for (int kk = 0; kk < 4; kk++) {
        float vvv[4];
        #pragma unroll
        for (int j = 0; j < 4; j++) vvv[j] = Vs[k + kk][tx + j * 16];
        #pragma unroll
        for (int i = 0; i < 4; i++)
          #pragma unroll
          for (int j = 0; j < 4; j++)
            Oacc[i][j] += pv[i][kk] * vvv[j];
      }
    }
    __syncthreads();   // done with KPs/Vs for this tile
  }

  #pragma unroll
  for (int i = 0; i < 4; i++) {
    const float inv = 1.0f / l_i[i];
    const int qg = qt * 64 + ty + i * 16;
    short* orow = out + (size_t)(b * 2048 + qg) * 1024 + h * 64;
    #pragma unroll
    for (int j = 0; j < 4; j++) orow[tx + j * 16] = f2bf(Oacc[i][j] * inv);
  }
}

extern "C" void kernel_launch(void* const* d_in, const int* in_sizes, int n_in,
                              void* d_out, int out_size, void* d_ws, size_t ws_size,
                              hipStream_t stream) {
  const float* hidden = (const float*)d_in[0];
  const float* w_attn = (const float*)d_in[1];
  const float* b_attn = (const float*)d_in[2];
  const float* w_proj = (const float*)d_in[3];
  const float* b_proj = (const float*)d_in[4];
  float* outp = (float*)d_out;

  char* ws = (char*)d_ws;
  short* hA     = (short*)(ws);
  short* wqkvT  = (short*)(ws + 8ull  * 1024 * 1024);
  short* wprojT = (short*)(ws + 14ull * 1024 * 1024);
  short* qkvb   = (short*)(ws + 16ull * 1024 * 1024);
  short* aout   = (short*)(ws + 40ull * 1024 * 1024);

  // hidden [4096,1024] fp32 -> bf16
  to_bf16_kernel<<<4096, 256, 0, stream>>>(hidden, hA);
  // w_attn [1024,3072] -> [3072,1024] bf16 ; w_proj [1024,1024] -> [1024,1024]
  transpose_to_bf16<<<dim3(96, 32), dim3(32, 8), 0, stream>>>(w_attn, wqkvT, 1024, 3072);
  transpose_to_bf16<<<dim3(32, 32), dim3(32, 8), 0, stream>>>(w_proj, wprojT, 1024, 1024);
  // qkv = hidden @ w_attn + b_attn  (bf16 out)
  gemm_bt<1><<<dim3(3072 / BN, 4096 / BM), 256, 0, stream>>>(hA, wqkvT, b_attn, qkvb, 4096, 3072, 1024);
  // causal flash attention per (b,h,q-tile)
  attn_kernel<<<dim3(32, 32), 256, 0, stream>>>(qkvb, aout);
  // out = attn @ w_proj + b_proj  (fp32 out)
  gemm_bt<0><<<dim3(1024 / BN, 4096 / BM), 256, 0, stream>>>(aout, wprojT, b_proj, outp, 4096, 1024, 1024);
}

// Round 2
// 249.087 us; speedup vs baseline: 5.0088x; 5.0088x over previous
//
#include <hip/hip_runtime.h>
#include <hip/hip_bf16.h>

// GPT2 attention: hidden[2,2048,1024] -> qkv gemm -> causal MFMA flash attn -> proj
// ws layout (48 MB):
//   hA/vT  bf16 8 MB @ 0      (hA consumed by gemm_qkv, then region reused as vT)
//   wqkvT  bf16 6 MB @ 8 MB
//   wprojT bf16 2 MB @ 14 MB
//   qkv    bf16 24 MB @ 16 MB
//   aout   bf16 8 MB @ 40 MB

typedef __attribute__((ext_vector_type(4))) float  float4v;
typedef __attribute__((ext_vector_type(8))) short  short8v;
typedef __attribute__((ext_vector_type(4))) short  short4v;

__device__ __forceinline__ short f2bf(float f) {
  union { float f; unsigned u; } v; v.f = f;
  unsigned r = v.u + 0x7fffu + ((v.u >> 16) & 1u);   // RNE
  return (short)(r >> 16);
}

// ---------------- fp32 -> bf16 convert (vectorized) ----------------
__global__ __launch_bounds__(256) void to_bf16_kernel(
    const float* __restrict__ in, short* __restrict__ out) {
  const size_t i = ((size_t)blockIdx.x * 256 + threadIdx.x) * 4;
  float4v v = *(const float4v*)(in + i);
  short4v o;
  #pragma unroll
  for (int k = 0; k < 4; k++) o[k] = f2bf(v[k]);
  *(short4v*)(out + i) = o;
}

// ---------------- fp32 [R,C] -> bf16 transposed [C,R] ----------------
__global__ __launch_bounds__(256) void transpose_to_bf16(
    const float* __restrict__ in, short* __restrict__ out, int R, int C) {
  __shared__ float tile[32][33];
  const int c0 = blockIdx.x * 32, r0 = blockIdx.y * 32;
  const int tx = threadIdx.x, ty = threadIdx.y;   // 32 x 8
  #pragma unroll
  for (int i = 0; i < 4; i++)
    tile[ty + i * 8][tx] = in[(size_t)(r0 + ty + i * 8) * C + c0 + tx];
  __syncthreads();
  #pragma unroll
  for (int i = 0; i < 4; i++) {
    const int cc = ty + i * 8;
    out[(size_t)(c0 + cc) * R + r0 + tx] = f2bf(tile[tx][cc]);
  }
}

// ---- bf16 transpose of the V slice of qkv: [s, d] -> vT[bh*64+d][s] ----
__global__ __launch_bounds__(256) void transpose_v(
    const short* __restrict__ qkv, short* __restrict__ vT) {
  __shared__ short T[64][72];
  const int st = blockIdx.x;   // s-tile of 64 (0..31)
  const int bh = blockIdx.y;   // 0..31
  const int b = bh >> 4, h = bh & 15;
  const int t = threadIdx.x;
  const int r = t >> 3, c = (t & 7) * 8;
  const size_t base = (size_t)b * 2048 * 3072 + 2048 + h * 64;
  #pragma unroll
  for (int half = 0; half < 2; half++) {
    const int row = r + half * 32;   // s within tile
    *(short8v*)&T[row][c] =
        *(const short8v*)(qkv + base + (size_t)(st * 64 + row) * 3072 + c);
  }
  __syncthreads();
  #pragma unroll
  for (int half = 0; half < 2; half++) {
    const int d = r + half * 32;
    short8v o;
    #pragma unroll
    for (int k = 0; k < 8; k++) o[k] = T[c + k][d];
    *(short8v*)(vT + (size_t)(bh * 64 + d) * 2048 + st * 64 + c) = o;
  }
}

// ---------------- bf16 MFMA GEMM-BT: C[M,N] = A[M,K] * Bt[N,K]^T + bias ----
#define BM 128
#define BN 128
#define BK 32
#define KPAD 8

template<int OUT_BF16>
__global__ __launch_bounds__(256) void gemm_bt(
    const short* __restrict__ A, const short* __restrict__ Bt,
    const float* __restrict__ bias, void* __restrict__ Cout,
    int M, int N, int K)
{
  __shared__ short As[BM][BK + KPAD];
  __shared__ short Bs[BN][BK + KPAD];
  const int t    = threadIdx.x;
  const int lane = t & 63;
  const int wave = t >> 6;
  const int wm   = (wave >> 1) * 64;
  const int wn   = (wave & 1) * 64;
  const int l16  = lane & 15;
  const int quad = lane >> 4;
  const int row0 = blockIdx.y * BM;
  const int col0 = blockIdx.x * BN;

  float4v acc[4][4] = {};

  const int r_ld = t >> 2;
  const int c_ld = (t & 3) * 8;

  for (int k0 = 0; k0 < K; k0 += BK) {
    #pragma unroll
    for (int half = 0; half < 2; half++) {
      const int r = r_ld + half * 64;
      *(short8v*)&As[r][c_ld] =
          *(const short8v*)(A  + (size_t)(row0 + r) * K + k0 + c_ld);
      *(short8v*)&Bs[r][c_ld] =
          *(const short8v*)(Bt + (size_t)(col0 + r) * K + k0 + c_ld);
    }
    __syncthreads();
    short8v af[4], bf[4];
    #pragma unroll
    for (int i = 0; i < 4; i++)
      af[i] = *(const short8v*)&As[wm + i * 16 + l16][quad * 8];
    #pragma unroll
    for (int j = 0; j < 4; j++)
      bf[j] = *(const short8v*)&Bs[wn + j * 16 + l16][quad * 8];
    #pragma unroll
    for (int i = 0; i < 4; i++)
      #pragma unroll
      for (int j = 0; j < 4; j++)
        acc[i][j] = __builtin_amdgcn_mfma_f32_16x16x32_bf16(af[i], bf[j], acc[i][j], 0, 0, 0);
    __syncthreads();
  }

  #pragma unroll
  for (int j = 0; j < 4; j++) {
    const int col = col0 + wn + j * 16 + l16;
    const float bv = bias[col];
    #pragma unroll
    for (int i = 0; i < 4; i++) {
      #pragma unroll
      for (int r = 0; r < 4; r++) {
        const int row = row0 + wm + i * 16 + quad * 4 + r;
        const float v = acc[i][j][r] + bv;
        if (OUT_BF16) ((short*)Cout)[(size_t)row * N + col] = f2bf(v);
        else          ((float*)Cout)[(size_t)row * N + col] = v;
      }
    }
  }
}

// ---------------- MFMA causal flash attention ----------------
// Block = one (b,h) x 128 q-rows; 4 waves x 32 q-rows each.
// K-tile = 64. Q frags in registers; P does a per-wave LDS round-trip
// (C-layout -> A-layout) in the Qs region (dead after Q frags lifted).
__global__ __launch_bounds__(256, 2) void attn_mfma(
    const short* __restrict__ qkv, const short* __restrict__ vT,
    short* __restrict__ out)
{
  __shared__ short QPs[128 * 72];   // Qs, then per-wave P (wave w: rows w*32..+31)
  __shared__ short Ks [64 * 72];
  __shared__ short Vts[64 * 72];

  const int bh = blockIdx.y;
  const int b = bh >> 4, h = bh & 15;
  int qi = blockIdx.x;
  if (b) qi = 15 - qi;              // pair heavy+light q-tiles on likely co-resident blocks
  const int t = threadIdx.x;
  const int lane = t & 63, w = t >> 6;
  const int l16 = lane & 15, quad = lane >> 4;

  const size_t base = (size_t)b * 2048 * 3072;
  const int qoff = h * 64, koff = 1024 + h * 64;
  const int q0 = qi * 128;

  // stage Q (128 x 64) into QPs (stride 72)
  {
    const int r = t >> 3, c = (t & 7) * 8;
    #pragma unroll
    for (int p = 0; p < 4; p++) {
      const int row = r + p * 32;
      *(short8v*)&QPs[row * 72 + c] =
          *(const short8v*)(qkv + base + (size_t)(q0 + row) * 3072 + qoff + c);
    }
  }
  __syncthreads();
  short8v qf[2][2];
  #pragma unroll
  for (int i = 0; i < 2; i++)
    #pragma unroll
    for (int ks = 0; ks < 2; ks++)
      qf[i][ks] = *(const short8v*)&QPs[(w * 32 + i * 16 + l16) * 72 + ks * 32 + quad * 8];

  float4v Oacc[2][4] = {};
  float m_i[2][4], l_i[2][4];
  #pragma unroll
  for (int i = 0; i < 2; i++)
    #pragma unroll
    for (int r2 = 0; r2 < 4; r2++) { m_i[i][r2] = -INFINITY; l_i[i][r2] = 0.0f; }

  const int ktn = 2 * qi + 2;
  const int wrow_max = q0 + w * 32 + 31;
  const int r_ld = t >> 3, c_ld = (t & 7) * 8;

  for (int kt = 0; kt < ktn; kt++) {
    #pragma unroll
    for (int half = 0; half < 2; half++) {
      const int row = r_ld + half * 32;
      *(short8v*)&Ks[row * 72 + c_ld] =
          *(const short8v*)(qkv + base + (size_t)(kt * 64 + row) * 3072 + koff + c_ld);
      *(short8v*)&Vts[row * 72 + c_ld] =
          *(const short8v*)(vT + (size_t)(bh * 64 + row) * 2048 + kt * 64 + c_ld);
    }
    __syncthreads();

    if (kt * 64 <= wrow_max) {      // wave-uniform: skip fully-masked tiles
      // S = Q K^T  (C-layout: col = l16, row = quad*4+r)
      float4v sa[2][4] = {};
      #pragma unroll
      for (int ks = 0; ks < 2; ks++)
        #pragma unroll
        for (int j = 0; j < 4; j++) {
          const short8v kf = *(const short8v*)&Ks[(j * 16 + l16) * 72 + ks * 32 + quad * 8];
          #pragma unroll
          for (int i = 0; i < 2; i++)
            sa[i][j] = __builtin_amdgcn_mfma_f32_16x16x32_bf16(qf[i][ks], kf, sa[i][j], 0, 0, 0);
        }

      #pragma unroll
      for (int i = 0; i < 2; i++) {
        const int rbase = q0 + w * 32 + i * 16;
        #pragma unroll
        for (int j = 0; j < 4; j++)
          #pragma unroll
          for (int r2 = 0; r2 < 4; r2++)
            sa[i][j][r2] *= 0.125f;               // 1/sqrt(64)
        if (kt * 64 + 63 > rbase) {               // causal mask (diagonal-ish tiles)
          #pragma unroll
          for (int j = 0; j < 4; j++) {
            const int col = kt * 64 + j * 16 + l16;
            #pragma unroll
            for (int r2 = 0; r2 < 4; r2++)
              if (col > rbase + quad * 4 + r2) sa[i][j][r2] = -INFINITY;
          }
        }
        // online softmax over rows quad*4+r2 (stats shared by the 16-lane group)
        float mx[4], mn[4], al[4], rs[4];
        #pragma unroll
        for (int r2 = 0; r2 < 4; r2++) {
          mx[r2] = fmaxf(fmaxf(sa[i][0][r2], sa[i][1][r2]),
                         fmaxf(sa[i][2][r2], sa[i][3][r2]));
          #pragma unroll
          for (int off = 1; off < 16; off <<= 1)
            mx[r2] = fmaxf(mx[r2], __shfl_xor(mx[r2], off));
          mn[r2] = fmaxf(m_i[i][r2], mx[r2]);
          al[r2] = __expf(m_i[i][r2] - mn[r2]);
          m_i[i][r2] = mn[r2];
          rs[r2] = 0.0f;
        }
        #pragma unroll
        for (int j = 0; j < 4; j++)
          #pragma unroll
          for (int r2 = 0; r2 < 4; r2++) {
            const float p = __expf(sa[i][j][r2] - mn[r2]);
            rs[r2] += p;
            QPs[(w * 32 + i * 16 + quad * 4 + r2) * 72 + j * 16 + l16] = f2bf(p);
          }
        #pragma unroll
        for (int r2 = 0; r2 < 4; r2++) {
          #pragma unroll
          for (int off = 1; off < 16; off <<= 1)
            rs[r2] += __shfl_xor(rs[r2], off);
          l_i[i][r2] = l_i[i][r2] * al[r2] + rs[r2];
          #pragma unroll
          for (int j = 0; j < 4; j++)
            Oacc[i][j][r2] *= al[r2];
        }
      }

      // O += P V   (P via per-wave LDS region; intra-wave DS pipe is in-order)
      #pragma unroll
      for (int ks = 0; ks < 2; ks++) {
        short8v pf[2];
        #pragma unroll
        for (int i = 0; i < 2; i++)
          pf[i] = *(const short8v*)&QPs[(w * 32 + i * 16 + l16) * 72 + ks * 32 + quad * 8];
        #pragma unroll
        for (int j = 0; j < 4; j++) {
          const short8v vf = *(const short8v*)&Vts[(j * 16 + l16) * 72 + ks * 32 + quad * 8];
          #pragma unroll
          for (int i = 0; i < 2; i++)
            Oacc[i][j] = __builtin_amdgcn_mfma_f32_16x16x32_bf16(pf[i], vf, Oacc[i][j], 0, 0, 0);
        }
      }
    }
    __syncthreads();
  }

  #pragma unroll
  for (int i = 0; i < 2; i++)
    #pragma unroll
    for (int r2 = 0; r2 < 4; r2++) {
      const float inv = 1.0f / l_i[i][r2];
      const int row = q0 + w * 32 + i * 16 + quad * 4 + r2;
      short* orow = out + (size_t)(b * 2048 + row) * 1024 + h * 64;
      #pragma unroll
      for (int j = 0; j < 4; j++)
        orow[j * 16 + l16] = f2bf(Oacc[i][j][r2] * inv);
    }
}

extern "C" void kernel_launch(void* const* d_in, const int* in_sizes, int n_in,
                              void* d_out, int out_size, void* d_ws, size_t ws_size,
                              hipStream_t stream) {
  const float* hidden = (const float*)d_in[0];
  const float* w_attn = (const float*)d_in[1];
  const float* b_attn = (const float*)d_in[2];
  const float* w_proj = (const float*)d_in[3];
  const float* b_proj = (const float*)d_in[4];
  float* outp = (float*)d_out;

  char* ws = (char*)d_ws;
  short* hA     = (short*)(ws);                       // 8 MB, dead after gemm_qkv
  short* vTbuf  = (short*)(ws);                       // reuses hA region
  short* wqkvT  = (short*)(ws + 8ull  * 1024 * 1024);
  short* wprojT = (short*)(ws + 14ull * 1024 * 1024);
  short* qkvb   = (short*)(ws + 16ull * 1024 * 1024);
  short* aout   = (short*)(ws + 40ull * 1024 * 1024);

  to_bf16_kernel<<<4096, 256, 0, stream>>>(hidden, hA);
  transpose_to_bf16<<<dim3(96, 32), dim3(32, 8), 0, stream>>>(w_attn, wqkvT, 1024, 3072);
  transpose_to_bf16<<<dim3(32, 32), dim3(32, 8), 0, stream>>>(w_proj, wprojT, 1024, 1024);
  gemm_bt<1><<<dim3(3072 / BN, 4096 / BM), 256, 0, stream>>>(hA, wqkvT, b_attn, qkvb, 4096, 3072, 1024);
  transpose_v<<<dim3(32, 32), 256, 0, stream>>>(qkvb, vTbuf);
  attn_mfma<<<dim3(16, 32), 256, 0, stream>>>(qkvb, vTbuf, aout);
  gemm_bt<0><<<dim3(1024 / BN, 4096 / BM), 256, 0, stream>>>(aout, wprojT, b_proj, outp, 4096, 1024, 1024);
}

// Round 3
// 246.749 us; speedup vs baseline: 5.0563x; 1.0095x over previous
//
#include <hip/hip_runtime.h>
#include <hip/hip_bf16.h>

// GPT2 attention: hidden[2,2048,1024] -> qkv gemm -> causal MFMA flash attn -> proj
// ws layout (48 MB):
//   hA/vT  bf16 8 MB @ 0      (hA consumed by gemm_qkv, then region reused as vT)
//   wqkvT  bf16 6 MB @ 8 MB
//   wprojT bf16 2 MB @ 14 MB
//   qkv    bf16 24 MB @ 16 MB
//   aout   bf16 8 MB @ 40 MB

typedef __attribute__((ext_vector_type(4))) float  float4v;
typedef __attribute__((ext_vector_type(8))) short  short8v;
typedef __attribute__((ext_vector_type(4))) short  short4v;

__device__ __forceinline__ short f2bf(float f) {
  union { float f; unsigned u; } v; v.f = f;
  unsigned r = v.u + 0x7fffu + ((v.u >> 16) & 1u);   // RNE
  return (short)(r >> 16);
}

// async global->LDS, 16B per lane; LDS dest = wave-uniform base + lane*16
__device__ __forceinline__ void gl_lds16(const void* g, void* l) {
  __builtin_amdgcn_global_load_lds(
      (const __attribute__((address_space(1))) unsigned*)g,
      (__attribute__((address_space(3))) unsigned*)l, 16, 0, 0);
}

// ---------------- fp32 -> bf16 convert (vectorized) ----------------
__global__ __launch_bounds__(256) void to_bf16_kernel(
    const float* __restrict__ in, short* __restrict__ out) {
  const size_t i = ((size_t)blockIdx.x * 256 + threadIdx.x) * 4;
  float4v v = *(const float4v*)(in + i);
  short4v o;
  #pragma unroll
  for (int k = 0; k < 4; k++) o[k] = f2bf(v[k]);
  *(short4v*)(out + i) = o;
}

// ---------------- fp32 [R,C] -> bf16 transposed [C,R] ----------------
__global__ __launch_bounds__(256) void transpose_to_bf16(
    const float* __restrict__ in, short* __restrict__ out, int R, int C) {
  __shared__ float tile[32][33];
  const int c0 = blockIdx.x * 32, r0 = blockIdx.y * 32;
  const int tx = threadIdx.x, ty = threadIdx.y;   // 32 x 8
  #pragma unroll
  for (int i = 0; i < 4; i++)
    tile[ty + i * 8][tx] = in[(size_t)(r0 + ty + i * 8) * C + c0 + tx];
  __syncthreads();
  #pragma unroll
  for (int i = 0; i < 4; i++) {
    const int cc = ty + i * 8;
    out[(size_t)(c0 + cc) * R + r0 + tx] = f2bf(tile[tx][cc]);
  }
}

// ---- bf16 transpose of the V slice of qkv: [s, d] -> vT[bh*64+d][s] ----
__global__ __launch_bounds__(256) void transpose_v(
    const short* __restrict__ qkv, short* __restrict__ vT) {
  __shared__ short T[64][72];
  const int st = blockIdx.x;   // s-tile of 64 (0..31)
  const int bh = blockIdx.y;   // 0..31
  const int b = bh >> 4, h = bh & 15;
  const int t = threadIdx.x;
  const int r = t >> 3, c = (t & 7) * 8;
  const size_t base = (size_t)b * 2048 * 3072 + 2048 + h * 64;
  #pragma unroll
  for (int half = 0; half < 2; half++) {
    const int row = r + half * 32;
    *(short8v*)&T[row][c] =
        *(const short8v*)(qkv + base + (size_t)(st * 64 + row) * 3072 + c);
  }
  __syncthreads();
  #pragma unroll
  for (int half = 0; half < 2; half++) {
    const int d = r + half * 32;
    short8v o;
    #pragma unroll
    for (int k = 0; k < 8; k++) o[k] = T[c + k][d];
    *(short8v*)(vT + (size_t)(bh * 64 + d) * 2048 + st * 64 + c) = o;
  }
}

// ---------------- bf16 MFMA GEMM-BT: C[M,N] = A[M,K] * Bt[N,K]^T + bias ----
// 128x128 tile, BK=32, global_load_lds width-16 staging (m97 structure).
// LDS unpadded (required: lds dest = wave base + lane*16).
template<int OUT_BF16>
__global__ __launch_bounds__(256) void gemm_bt(
    const short* __restrict__ A, const short* __restrict__ Bt,
    const float* __restrict__ bias, void* __restrict__ Cout,
    int M, int N, int K)
{
  __shared__ short As[128][32];
  __shared__ short Bs[128][32];
  const int t    = threadIdx.x;
  const int lane = t & 63;
  const int wave = t >> 6;
  const int wm   = (wave >> 1) * 64;
  const int wn   = (wave & 1) * 64;
  const int l16  = lane & 15;
  const int quad = lane >> 4;
  const int row0 = blockIdx.y * 128;
  const int col0 = blockIdx.x * 128;

  float4v acc[4][4] = {};

  // wave stages A rows [wave*32, wave*32+32), same for B; 2 insts each
  const int srow = lane >> 2;          // 0..15
  const int scol = (lane & 3) * 8;     // shorts
  const short* gA = A  + (size_t)(row0 + wave * 32 + srow) * K + scol;
  const short* gB = Bt + (size_t)(col0 + wave * 32 + srow) * K + scol;

  for (int k0 = 0; k0 < K; k0 += 32) {
    #pragma unroll
    for (int h = 0; h < 2; h++) {
      gl_lds16(gA + (size_t)(h * 16) * K + k0, &As[wave * 32 + h * 16][0]);
      gl_lds16(gB + (size_t)(h * 16) * K + k0, &Bs[wave * 32 + h * 16][0]);
    }
    __syncthreads();
    short8v af[4], bf[4];
    #pragma unroll
    for (int i = 0; i < 4; i++)
      af[i] = *(const short8v*)&As[wm + i * 16 + l16][quad * 8];
    #pragma unroll
    for (int j = 0; j < 4; j++)
      bf[j] = *(const short8v*)&Bs[wn + j * 16 + l16][quad * 8];
    #pragma unroll
    for (int i = 0; i < 4; i++)
      #pragma unroll
      for (int j = 0; j < 4; j++)
        acc[i][j] = __builtin_amdgcn_mfma_f32_16x16x32_bf16(af[i], bf[j], acc[i][j], 0, 0, 0);
    __syncthreads();
  }

  #pragma unroll
  for (int j = 0; j < 4; j++) {
    const int col = col0 + wn + j * 16 + l16;
    const float bv = bias[col];
    #pragma unroll
    for (int i = 0; i < 4; i++) {
      #pragma unroll
      for (int r = 0; r < 4; r++) {
        const int row = row0 + wm + i * 16 + quad * 4 + r;
        const float v = acc[i][j][r] + bv;
        if (OUT_BF16) ((short*)Cout)[(size_t)row * N + col] = f2bf(v);
        else          ((float*)Cout)[(size_t)row * N + col] = v;
      }
    }
  }
}

// ---------------- MFMA causal flash attention, pair-balanced ----------------
// Block = (b,h) x q-tile pair (p, 31-p), 64 rows each -> 33 MFMA-phases/block
// uniformly. 4 waves; wave w owns rows [w*16, w*16+16) of BOTH tiles.
// P round-trips C-layout -> A-layout through the (dead) Q region per wave.
#define ATT_SCALE 0.18033688011112042f   // log2(e) / sqrt(64)

__device__ __forceinline__ void attn_tile(
    const short8v qf[2], const short* __restrict__ Ks,
    const short* __restrict__ Vts, short* __restrict__ Preg,
    int l16, int quad, int rbase, int c0, bool masked,
    float4v (&Oacc)[4], float (&m_i)[4], float (&l_i)[4])
{
  float4v sa[4] = {};
  #pragma unroll
  for (int ks = 0; ks < 2; ks++)
    #pragma unroll
    for (int j = 0; j < 4; j++) {
      const short8v kf = *(const short8v*)&Ks[(j * 16 + l16) * 72 + ks * 32 + quad * 8];
      sa[j] = __builtin_amdgcn_mfma_f32_16x16x32_bf16(qf[ks], kf, sa[j], 0, 0, 0);
    }
  if (masked) {
    #pragma unroll
    for (int j = 0; j < 4; j++) {
      const int col = c0 + j * 16 + l16;
      #pragma unroll
      for (int r2 = 0; r2 < 4; r2++)
        if (col > rbase + quad * 4 + r2) sa[j][r2] = -INFINITY;
    }
  }
  float mn[4], al[4], rs[4];
  #pragma unroll
  for (int r2 = 0; r2 < 4; r2++) {
    float mx = fmaxf(fmaxf(sa[0][r2], sa[1][r2]), fmaxf(sa[2][r2], sa[3][r2]));
    #pragma unroll
    for (int off = 1; off < 16; off <<= 1) mx = fmaxf(mx, __shfl_xor(mx, off));
    mn[r2] = fmaxf(m_i[r2], mx * ATT_SCALE);
    al[r2] = exp2f(m_i[r2] - mn[r2]);
    m_i[r2] = mn[r2];
    rs[r2] = 0.0f;
  }
  #pragma unroll
  for (int j = 0; j < 4; j++)
    #pragma unroll
    for (int r2 = 0; r2 < 4; r2++) {
      const float pp = exp2f(fmaf(sa[j][r2], ATT_SCALE, -mn[r2]));
      rs[r2] += pp;
      Preg[(quad * 4 + r2) * 72 + j * 16 + l16] = f2bf(pp);
    }
  #pragma unroll
  for (int r2 = 0; r2 < 4; r2++) {
    #pragma unroll
    for (int off = 1; off < 16; off <<= 1) rs[r2] += __shfl_xor(rs[r2], off);
    l_i[r2] = l_i[r2] * al[r2] + rs[r2];
    #pragma unroll
    for (int j = 0; j < 4; j++) Oacc[j][r2] *= al[r2];
  }
  // O += P V  (per-wave LDS region; intra-wave DS pipe is in-order)
  #pragma unroll
  for (int ks = 0; ks < 2; ks++) {
    const short8v pf = *(const short8v*)&Preg[l16 * 72 + ks * 32 + quad * 8];
    #pragma unroll
    for (int j = 0; j < 4; j++) {
      const short8v vf = *(const short8v*)&Vts[(j * 16 + l16) * 72 + ks * 32 + quad * 8];
      Oacc[j] = __builtin_amdgcn_mfma_f32_16x16x32_bf16(pf, vf, Oacc[j], 0, 0, 0);
    }
  }
}

__global__ __launch_bounds__(256, 2) void attn_mfma(
    const short* __restrict__ qkv, const short* __restrict__ vT,
    short* __restrict__ out)
{
  __shared__ short QPs[128 * 72];   // rows 0..63: Ta Q/P, 64..127: Tb Q/P
  __shared__ short Ks [64 * 72];
  __shared__ short Vts[64 * 72];    // [d][s]

  const int bh = blockIdx.y;
  const int b = bh >> 4, h = bh & 15;
  const int p = blockIdx.x;         // 0..15: pair (p, 31-p)
  const int t = threadIdx.x;
  const int lane = t & 63, w = t >> 6;
  const int l16 = lane & 15, quad = lane >> 4;

  const size_t base = (size_t)b * 2048 * 3072;
  const int qoff = h * 64, koff = 1024 + h * 64;
  const int qa0 = p * 64;           // early tile
  const int qb0 = (31 - p) * 64;    // late tile (active all iterations)

  // stage Q for both tiles
  {
    const int r = t >> 3, c = (t & 7) * 8;
    #pragma unroll
    for (int hh = 0; hh < 2; hh++) {
      const int row = r + hh * 32;
      *(short8v*)&QPs[row * 72 + c] =
          *(const short8v*)(qkv + base + (size_t)(qa0 + row) * 3072 + qoff + c);
      *(short8v*)&QPs[(64 + row) * 72 + c] =
          *(const short8v*)(qkv + base + (size_t)(qb0 + row) * 3072 + qoff + c);
    }
  }
  __syncthreads();
  short8v qfA[2], qfB[2];
  #pragma unroll
  for (int ks = 0; ks < 2; ks++) {
    qfA[ks] = *(const short8v*)&QPs[(w * 16 + l16) * 72 + ks * 32 + quad * 8];
    qfB[ks] = *(const short8v*)&QPs[(64 + w * 16 + l16) * 72 + ks * 32 + quad * 8];
  }

  float4v OA[4] = {}, OB[4] = {};
  float mA[4], lA[4], mB[4], lB[4];
  #pragma unroll
  for (int r2 = 0; r2 < 4; r2++) {
    mA[r2] = -INFINITY; lA[r2] = 0.0f;
    mB[r2] = -INFINITY; lB[r2] = 0.0f;
  }

  const int KTN = 32 - p;           // Tb needs kt <= 31-p: every iteration
  const int r_ld = t >> 3, c_ld = (t & 7) * 8;

  for (int kt = 0; kt < KTN; kt++) {
    #pragma unroll
    for (int hh = 0; hh < 2; hh++) {
      const int row = r_ld + hh * 32;
      *(short8v*)&Ks[row * 72 + c_ld] =
          *(const short8v*)(qkv + base + (size_t)(kt * 64 + row) * 3072 + koff + c_ld);
      *(short8v*)&Vts[row * 72 + c_ld] =
          *(const short8v*)(vT + (size_t)(bh * 64 + row) * 2048 + kt * 64 + c_ld);
    }
    __syncthreads();
    const int c0 = kt * 64;
    if (kt <= p)                    // block-uniform
      attn_tile(qfA, Ks, Vts, &QPs[(w * 16) * 72], l16, quad,
                qa0 + w * 16, c0, kt == p, OA, mA, lA);
    attn_tile(qfB, Ks, Vts, &QPs[(64 + w * 16) * 72], l16, quad,
              qb0 + w * 16, c0, kt == KTN - 1, OB, mB, lB);
    __syncthreads();
  }

  #pragma unroll
  for (int r2 = 0; r2 < 4; r2++) {
    const float ivA = 1.0f / lA[r2], ivB = 1.0f / lB[r2];
    const int ra = qa0 + w * 16 + quad * 4 + r2;
    const int rb = qb0 + w * 16 + quad * 4 + r2;
    short* oa = out + (size_t)(b * 2048 + ra) * 1024 + h * 64;
    short* ob = out + (size_t)(b * 2048 + rb) * 1024 + h * 64;
    #pragma unroll
    for (int j = 0; j < 4; j++) {
      oa[j * 16 + l16] = f2bf(OA[j][r2] * ivA);
      ob[j * 16 + l16] = f2bf(OB[j][r2] * ivB);
    }
  }
}

extern "C" void kernel_launch(void* const* d_in, const int* in_sizes, int n_in,
                              void* d_out, int out_size, void* d_ws, size_t ws_size,
                              hipStream_t stream) {
  const float* hidden = (const float*)d_in[0];
  const float* w_attn = (const float*)d_in[1];
  const float* b_attn = (const float*)d_in[2];
  const float* w_proj = (const float*)d_in[3];
  const float* b_proj = (const float*)d_in[4];
  float* outp = (float*)d_out;

  char* ws = (char*)d_ws;
  short* hA     = (short*)(ws);                       // dead after gemm_qkv
  short* vTbuf  = (short*)(ws);                       // reuses hA region
  short* wqkvT  = (short*)(ws + 8ull  * 1024 * 1024);
  short* wprojT = (short*)(ws + 14ull * 1024 * 1024);
  short* qkvb   = (short*)(ws + 16ull * 1024 * 1024);
  short* aout   = (short*)(ws + 40ull * 1024 * 1024);

  to_bf16_kernel<<<4096, 256, 0, stream>>>(hidden, hA);
  transpose_to_bf16<<<dim3(96, 32), dim3(32, 8), 0, stream>>>(w_attn, wqkvT, 1024, 3072);
  transpose_to_bf16<<<dim3(32, 32), dim3(32, 8), 0, stream>>>(w_proj, wprojT, 1024, 1024);
  gemm_bt<1><<<dim3(24, 32), 256, 0, stream>>>(hA, wqkvT, b_attn, qkvb, 4096, 3072, 1024);
  transpose_v<<<dim3(32, 32), 256, 0, stream>>>(qkvb, vTbuf);
  attn_mfma<<<dim3(16, 32), 256, 0, stream>>>(qkvb, vTbuf, aout);
  gemm_bt<0><<<dim3(8, 32), 256, 0, stream>>>(aout, wprojT, b_proj, outp, 4096, 1024, 1024);
}

// Round 4
// 226.062 us; speedup vs baseline: 5.5190x; 1.0915x over previous
//
#include <hip/hip_runtime.h>
#include <hip/hip_bf16.h>

// GPT2 attention: hidden[2,2048,1024] -> qkv gemm -> causal MFMA flash attn -> proj
// ws layout (48 MB):
//   hA/vA  bf16 8 MB @ 0      (hA consumed by gemm_qkv, then region reused as vA)
//   wqkvT  bf16 6 MB @ 8 MB
//   wprojT bf16 2 MB @ 14 MB
//   qkv    bf16 24 MB @ 16 MB
//   aout   bf16 8 MB @ 40 MB
//
// Attention computes S^T = K*Q^T so P^T exits QK in exactly the B-operand
// fragment layout of mfma_16x16x16bf16 (k = quad*4+reg): P stays in registers.
// PV is O^T = V^T * P^T with V^T staged in fragment-major chunks (lane*16B
// contiguous -> conflict-free, gl_lds16-compatible).

typedef __attribute__((ext_vector_type(4))) float  float4v;
typedef __attribute__((ext_vector_type(8))) short  short8v;
typedef __attribute__((ext_vector_type(4))) short  short4v;

__device__ __forceinline__ short f2bf(float f) {
  union { float f; unsigned u; } v; v.f = f;
  unsigned r = v.u + 0x7fffu + ((v.u >> 16) & 1u);   // RNE
  return (short)(r >> 16);
}

// async global->LDS, 16B per lane; LDS dest = wave-uniform base + lane*16
__device__ __forceinline__ void gl_lds16(const void* g, void* l) {
  __builtin_amdgcn_global_load_lds(
      (const __attribute__((address_space(1))) unsigned*)g,
      (__attribute__((address_space(3))) unsigned*)l, 16, 0, 0);
}

// ---------------- fp32 -> bf16 convert (vectorized) ----------------
__global__ __launch_bounds__(256) void to_bf16_kernel(
    const float* __restrict__ in, short* __restrict__ out) {
  const size_t i = ((size_t)blockIdx.x * 256 + threadIdx.x) * 4;
  float4v v = *(const float4v*)(in + i);
  short4v o;
  #pragma unroll
  for (int k = 0; k < 4; k++) o[k] = f2bf(v[k]);
  *(short4v*)(out + i) = o;
}

// ---------------- fp32 [R,C] -> bf16 transposed [C,R] ----------------
__global__ __launch_bounds__(256) void transpose_to_bf16(
    const float* __restrict__ in, short* __restrict__ out, int R, int C) {
  __shared__ float tile[32][33];
  const int c0 = blockIdx.x * 32, r0 = blockIdx.y * 32;
  const int tx = threadIdx.x, ty = threadIdx.y;   // 32 x 8
  #pragma unroll
  for (int i = 0; i < 4; i++)
    tile[ty + i * 8][tx] = in[(size_t)(r0 + ty + i * 8) * C + c0 + tx];
  __syncthreads();
  #pragma unroll
  for (int i = 0; i < 4; i++) {
    const int cc = ty + i * 8;
    out[(size_t)(c0 + cc) * R + r0 + tx] = f2bf(tile[tx][cc]);
  }
}

// ---- V slice of qkv -> fragment-major vA[bh][kt][chunk(kwp*4+dm)][lane][8] ----
// chunk lane (l16,quad) holds V^T[d = dm*16+l16][kv = kt*64 + kwp*32 + kw*16 + quad*4 + r]
// as {kw=0: r=0..3, kw=1: r=0..3}  (16B per lane, chunk = 1KB contiguous)
__global__ __launch_bounds__(256) void transpose_v(
    const short* __restrict__ qkv, short* __restrict__ vA) {
  __shared__ short T[64][72];
  const int st = blockIdx.x;   // kv-tile of 64 (0..31)
  const int bh = blockIdx.y;   // 0..31
  const int b = bh >> 4, h = bh & 15;
  const int t = threadIdx.x;
  const int r = t >> 3, c = (t & 7) * 8;
  const size_t base = (size_t)b * 2048 * 3072 + 2048 + h * 64;
  #pragma unroll
  for (int half = 0; half < 2; half++) {
    const int row = r + half * 32;
    *(short8v*)&T[row][c] =
        *(const short8v*)(qkv + base + (size_t)(st * 64 + row) * 3072 + c);
  }
  __syncthreads();
  const int lane = t & 63, dm = t >> 6;
  const int l16 = lane & 15, quad = lane >> 4;
  #pragma unroll
  for (int kwp = 0; kwp < 2; kwp++) {
    short8v o;
    #pragma unroll
    for (int r2 = 0; r2 < 4; r2++) {
      o[r2]     = T[kwp * 32 + quad * 4 + r2][dm * 16 + l16];
      o[4 + r2] = T[kwp * 32 + 16 + quad * 4 + r2][dm * 16 + l16];
    }
    *(short8v*)(vA + (((size_t)(bh * 32 + st) * 8 + kwp * 4 + dm) * 64 + lane) * 8) = o;
  }
}

// ---------------- bf16 MFMA GEMM-BT: C[M,N] = A[M,K] * Bt[N,K]^T + bias ----
// RBxBN=128 tile, BK=32, global_load_lds width-16 staging. RB = 128 or 64.
template<int RB, int OUT_BF16>
__global__ __launch_bounds__(256) void gemm_bt(
    const short* __restrict__ A, const short* __restrict__ Bt,
    const float* __restrict__ bias, void* __restrict__ Cout,
    int M, int N, int K)
{
  __shared__ short As[RB][32];
  __shared__ short Bs[128][32];
  const int MI = RB / 32;                 // 4 or 2 row-blocks of 16 per wave
  const int t    = threadIdx.x;
  const int lane = t & 63;
  const int wave = t >> 6;
  const int wm   = (wave >> 1) * (RB / 2);
  const int wn   = (wave & 1) * 64;
  const int l16  = lane & 15;
  const int quad = lane >> 4;
  const int row0 = blockIdx.y * RB;
  const int col0 = blockIdx.x * 128;

  float4v acc[MI][4] = {};

  const int srow = lane >> 2;          // 0..15
  const int scol = (lane & 3) * 8;     // shorts

  for (int k0 = 0; k0 < K; k0 += 32) {
    if (RB == 128) {
      #pragma unroll
      for (int h = 0; h < 2; h++)
        gl_lds16(A + (size_t)(row0 + wave * 32 + h * 16 + srow) * K + k0 + scol,
                 &As[(wave * 32 + h * 16 + srow) & (RB - 1)][scol]);
    } else {
      gl_lds16(A + (size_t)(row0 + wave * 16 + srow) * K + k0 + scol,
               &As[(wave * 16 + srow) & (RB - 1)][scol]);
    }
    #pragma unroll
    for (int h = 0; h < 2; h++)
      gl_lds16(Bt + (size_t)(col0 + wave * 32 + h * 16 + srow) * K + k0 + scol,
               &Bs[wave * 32 + h * 16 + srow][scol]);
    __syncthreads();
    short8v af[MI], bf[4];
    #pragma unroll
    for (int i = 0; i < MI; i++)
      af[i] = *(const short8v*)&As[wm + i * 16 + l16][quad * 8];
    #pragma unroll
    for (int j = 0; j < 4; j++)
      bf[j] = *(const short8v*)&Bs[wn + j * 16 + l16][quad * 8];
    #pragma unroll
    for (int i = 0; i < MI; i++)
      #pragma unroll
      for (int j = 0; j < 4; j++)
        acc[i][j] = __builtin_amdgcn_mfma_f32_16x16x32_bf16(af[i], bf[j], acc[i][j], 0, 0, 0);
    __syncthreads();
  }

  #pragma unroll
  for (int j = 0; j < 4; j++) {
    const int col = col0 + wn + j * 16 + l16;
    const float bv = bias[col];
    #pragma unroll
    for (int i = 0; i < MI; i++) {
      #pragma unroll
      for (int r = 0; r < 4; r++) {
        const int row = row0 + wm + i * 16 + quad * 4 + r;
        const float v = acc[i][j][r] + bv;
        if (OUT_BF16) ((short*)Cout)[(size_t)row * N + col] = f2bf(v);
        else          ((float*)Cout)[(size_t)row * N + col] = v;
      }
    }
  }
}

// ---------------- MFMA causal flash attention, S^T formulation ----------------
#define ATT_SCALE 0.18033688011112042f   // log2(e) / sqrt(64)

// per-tile softmax update; thread owns one q (= its l16), S values sa[jm][r]
// at kv = c0 + jm*16 + quad*4 + r. Emits P^T packed as PV B-frags pk[kw].
__device__ __forceinline__ void softmax_update(
    float4v (&sa)[4], int quad, int c0, int qg, bool masked,
    float& m_i, float& l_i, float4v (&O)[4], short4v (&pk)[4])
{
  if (masked) {
    #pragma unroll
    for (int jm = 0; jm < 4; jm++)
      #pragma unroll
      for (int r = 0; r < 4; r++)
        if (c0 + jm * 16 + quad * 4 + r > qg) sa[jm][r] = -INFINITY;
  }
  float mx = -INFINITY;
  #pragma unroll
  for (int jm = 0; jm < 4; jm++)
    #pragma unroll
    for (int r = 0; r < 4; r++) mx = fmaxf(mx, sa[jm][r]);
  mx = fmaxf(mx, __shfl_xor(mx, 16));
  mx = fmaxf(mx, __shfl_xor(mx, 32));
  const float mn = fmaxf(m_i, mx * ATT_SCALE);
  const float al = exp2f(m_i - mn);
  m_i = mn;
  float rs = 0.0f;
  #pragma unroll
  for (int jm = 0; jm < 4; jm++)
    #pragma unroll
    for (int r = 0; r < 4; r++) {
      const float pp = exp2f(fmaf(sa[jm][r], ATT_SCALE, -mn));
      rs += pp;
      pk[jm][r] = f2bf(pp);
    }
  rs += __shfl_xor(rs, 16);
  rs += __shfl_xor(rs, 32);
  l_i = l_i * al + rs;
  #pragma unroll
  for (int dm = 0; dm < 4; dm++)
    #pragma unroll
    for (int r = 0; r < 4; r++) O[dm][r] *= al;
}

__global__ __launch_bounds__(256, 2) void attn_mfma(
    const short* __restrict__ qkv, const short* __restrict__ vA,
    short* __restrict__ out)
{
  __shared__ short KA[8 * 512];   // 8 frag-major chunks x 1KB; chunk id = ks*4+jm
  __shared__ short VA[8 * 512];   // chunk id = kwp*4+dm

  const int bh = blockIdx.y;
  const int b = bh >> 4, h = bh & 15;
  const int p = blockIdx.x;       // pair (p, 31-p): uniform 33 tile-phases/block
  const int t = threadIdx.x;
  const int lane = t & 63, w = t >> 6;
  const int l16 = lane & 15, quad = lane >> 4;

  const size_t base = (size_t)b * 2048 * 3072;
  const int qoff = h * 64, koff = 1024 + h * 64;
  const int qa0 = p * 64, qb0 = (31 - p) * 64;
  const int qgA = qa0 + w * 16 + l16;     // this thread's q for tile A
  const int qgB = qb0 + w * 16 + l16;

  // Q B-frags straight from global (no LDS)
  short8v qfA[2], qfB[2];
  #pragma unroll
  for (int ks = 0; ks < 2; ks++) {
    qfA[ks] = *(const short8v*)(qkv + base + (size_t)qgA * 3072 + qoff + ks * 32 + quad * 8);
    qfB[ks] = *(const short8v*)(qkv + base + (size_t)qgB * 3072 + qoff + ks * 32 + quad * 8);
  }

  float4v OA[4] = {}, OB[4] = {};
  float mA = -INFINITY, lA = 0.0f, mB = -INFINITY, lB = 0.0f;

  const int KTN = 32 - p;

  for (int kt = 0; kt < KTN; kt++) {
    // stage K (rows->frag chunks) and V (already frag-major) via gl_lds16
    #pragma unroll
    for (int c = 0; c < 2; c++) {
      const int id = w * 2 + c;
      const int jm = id & 3, ks = id >> 2;
      gl_lds16(qkv + base + (size_t)(kt * 64 + jm * 16 + l16) * 3072 + koff + ks * 32 + quad * 8,
               &KA[id * 512 + lane * 8]);
      gl_lds16(vA + ((size_t)(bh * 32 + kt) * 8 + id) * 512 + lane * 8,
               &VA[id * 512 + lane * 8]);
    }
    __syncthreads();

    const bool doA = (kt <= p);          // block-uniform
    // S^T = K * Q^T : A-operand = K frags (shared by both tiles)
    float4v sA[4] = {}, sB[4] = {};
    #pragma unroll
    for (int ks = 0; ks < 2; ks++)
      #pragma unroll
      for (int jm = 0; jm < 4; jm++) {
        const short8v kf = *(const short8v*)&KA[(ks * 4 + jm) * 512 + lane * 8];
        sB[jm] = __builtin_amdgcn_mfma_f32_16x16x32_bf16(kf, qfB[ks], sB[jm], 0, 0, 0);
        if (doA)
          sA[jm] = __builtin_amdgcn_mfma_f32_16x16x32_bf16(kf, qfA[ks], sA[jm], 0, 0, 0);
      }

    const int c0 = kt * 64;
    short4v pA[4], pB[4];
    softmax_update(sB, quad, c0, qgB, kt == KTN - 1, mB, lB, OB, pB);
    if (doA) softmax_update(sA, quad, c0, qgA, kt == p, mA, lA, OA, pA);

    // O^T += V^T * P^T : A-operand = V frags (shared), B = P^T in registers
    #pragma unroll
    for (int id = 0; id < 8; id++) {
      const int kwp = id >> 2, dm = id & 3;
      const short8v vv = *(const short8v*)&VA[id * 512 + lane * 8];
      const short4v v0 = {vv[0], vv[1], vv[2], vv[3]};
      const short4v v1 = {vv[4], vv[5], vv[6], vv[7]};
      OB[dm] = __builtin_amdgcn_mfma_f32_16x16x16bf16_1k(v0, pB[kwp * 2],     OB[dm], 0, 0, 0);
      OB[dm] = __builtin_amdgcn_mfma_f32_16x16x16bf16_1k(v1, pB[kwp * 2 + 1], OB[dm], 0, 0, 0);
      if (doA) {
        OA[dm] = __builtin_amdgcn_mfma_f32_16x16x16bf16_1k(v0, pA[kwp * 2],     OA[dm], 0, 0, 0);
        OA[dm] = __builtin_amdgcn_mfma_f32_16x16x16bf16_1k(v1, pA[kwp * 2 + 1], OA[dm], 0, 0, 0);
      }
    }
    __syncthreads();
  }

  // epilogue: O^T regs -> out[q][d]; thread q = l16, d = dm*16 + quad*4 + r
  const float ivA = 1.0f / lA, ivB = 1.0f / lB;
  short* oa = out + (size_t)(b * 2048 + qgA) * 1024 + h * 64;
  short* ob = out + (size_t)(b * 2048 + qgB) * 1024 + h * 64;
  #pragma unroll
  for (int dm = 0; dm < 4; dm++) {
    short4v a4, b4;
    #pragma unroll
    for (int r = 0; r < 4; r++) {
      a4[r] = f2bf(OA[dm][r] * ivA);
      b4[r] = f2bf(OB[dm][r] * ivB);
    }
    *(short4v*)(oa + dm * 16 + quad * 4) = a4;
    *(short4v*)(ob + dm * 16 + quad * 4) = b4;
  }
}

extern "C" void kernel_launch(void* const* d_in, const int* in_sizes, int n_in,
                              void* d_out, int out_size, void* d_ws, size_t ws_size,
                              hipStream_t stream) {
  const float* hidden = (const float*)d_in[0];
  const float* w_attn = (const float*)d_in[1];
  const float* b_attn = (const float*)d_in[2];
  const float* w_proj = (const float*)d_in[3];
  const float* b_proj = (const float*)d_in[4];
  float* outp = (float*)d_out;

  char* ws = (char*)d_ws;
  short* hA     = (short*)(ws);                       // dead after gemm_qkv
  short* vAbuf  = (short*)(ws);                       // reuses hA region (8 MB)
  short* wqkvT  = (short*)(ws + 8ull  * 1024 * 1024);
  short* wprojT = (short*)(ws + 14ull * 1024 * 1024);
  short* qkvb   = (short*)(ws + 16ull * 1024 * 1024);
  short* aout   = (short*)(ws + 40ull * 1024 * 1024);

  to_bf16_kernel<<<4096, 256, 0, stream>>>(hidden, hA);
  transpose_to_bf16<<<dim3(96, 32), dim3(32, 8), 0, stream>>>(w_attn, wqkvT, 1024, 3072);
  transpose_to_bf16<<<dim3(32, 32), dim3(32, 8), 0, stream>>>(w_proj, wprojT, 1024, 1024);
  gemm_bt<128, 1><<<dim3(24, 32), 256, 0, stream>>>(hA, wqkvT, b_attn, qkvb, 4096, 3072, 1024);
  transpose_v<<<dim3(32, 32), 256, 0, stream>>>(qkvb, vAbuf);
  attn_mfma<<<dim3(16, 32), 256, 0, stream>>>(qkvb, vAbuf, aout);
  gemm_bt<64, 0><<<dim3(8, 64), 256, 0, stream>>>(aout, wprojT, b_proj, outp, 4096, 1024, 1024);
}